// Round 4
// baseline (250.378 us; speedup 1.0000x reference)
//
#include <hip/hip_runtime.h>
#include <hip/hip_bf16.h>

#define NROWS 262144
#define DDIM 256
#define HDIM 256
#define ADIM 64
#define LSEG 128
#define NSEG 2048
#define EPSF 1e-6f
#define TM 64                     // rows per MLP tile

typedef __attribute__((ext_vector_type(8))) short bf16x8;
typedef __attribute__((ext_vector_type(4))) float f32x4;

__device__ __forceinline__ unsigned short f2bf(float x){
  unsigned u = __float_as_uint(x);
  u += 0x7FFFu + ((u >> 16) & 1u);   // round-to-nearest-even
  return (unsigned short)(u >> 16);
}

// packed f32x2 -> bf16x2 (compiler lowers to v_cvt_pk_bf16_f32)
__device__ __forceinline__ unsigned int pk2bf(float a, float b){
  union { __hip_bfloat162 h2; unsigned int u; } cv;
  cv.h2 = __float22bfloat162_rn(make_float2(a, b));
  return cv.u;
}

// Weight prepack, fragment-major (validated: absmax 1.9e-6):
// dst[(((h>>4)*8 + (k>>5))*64 + ((k>>3)&3)*16 + (h&15))*8 + (k&7)] = bf16(W[h][k])
__device__ __forceinline__ int fragidx(int h, int k){
  return (((h >> 4)*8 + (k >> 5))*64 + ((k >> 3) & 3)*16 + (h & 15))*8 + (k & 7);
}

// W0-only variant: interleave h within each 32-col wave group so the two
// nt-fragments of a wave produce ADJACENT h columns (h = base + 2*frow + htl)
// -> L0 epilogue writes H as packed dwords. Correctness-verified R1-R3.
__device__ __forceinline__ int fragidx0(int h, int k){
  int hh = (h & ~31) | ((h & 1) << 4) | ((h & 31) >> 1);
  return fragidx(hh, k);
}

__global__ void cvt4_kernel(const float* __restrict__ s0, const float* __restrict__ s1,
                            const float* __restrict__ s2, const float* __restrict__ s3,
                            unsigned short* __restrict__ d0, unsigned short* __restrict__ d1,
                            unsigned short* __restrict__ d2, unsigned short* __restrict__ d3){
  int i = blockIdx.x * blockDim.x + threadIdx.x;
  if(i < 65536){                       // W0k [256][256] (h-interleaved)
    d0[fragidx0(i >> 8, i & 255)] = f2bf(s0[i]);
  } else if(i < 81920){                // W1k [64][256]
    int j = i - 65536;
    d1[fragidx(j >> 8, j & 255)] = f2bf(s1[j]);
  } else if(i < 147456){               // W0q (h-interleaved)
    int j = i - 81920;
    d2[fragidx0(j >> 8, j & 255)] = f2bf(s2[j]);
  } else {                             // W1q
    int j = i - 147456;
    d3[fragidx(j >> 8, j & 255)] = f2bf(s3[j]);
  }
}

// FUSED kernel (R21): one block per 128-row segment. MLP phase (4 tiles of
// TM=64: k-half0, k-half1, q-half0, q-half1) writes K/Q bf16 fragments
// DIRECTLY into LDS in seg's [128][72] layout — eliminating the 67 MB OUT
// write + 67 MB seg re-read + launch gap (~25 us of traffic; seg was
// measured AT the HBM roofline, so traffic removal is the only seg lever).
// LDS: single-buffered X/H (33.8 KB, H aliases consumed X) + kq (36.9 KB)
// = 70.7 KB -> 2 blocks/CU preserved. Single-buffer costs 4 barriers/tile
// (X-wr->rd, X-rd->H-wr, H-wr->rd, H-rd->X-wr) vs 2 before.
// Numerics are bit-identical to the split version (same pk2bf rounding of
// acc2+bias, same seg code). __launch_bounds__(512,2) REQUIRED (R8/R10/R15).
__global__ __launch_bounds__(512, 2) void fused_kernel(
    const float* __restrict__ Xk, const float* __restrict__ Xq,
    const unsigned short* __restrict__ W0k, const float* __restrict__ B0k,
    const unsigned short* __restrict__ W1k, const float* __restrict__ B1k,
    const unsigned short* __restrict__ W0q, const float* __restrict__ B0q,
    const unsigned short* __restrict__ W1q, const float* __restrict__ B1q,
    float* __restrict__ Wout, float* __restrict__ lossp)
{
  // [0, 33792)          xbuf: X tile bf16 [64][264] (H aliases it)
  // [33792, 70656)      kq:   [2][128][72] bf16  (kt, then qt)
  // seg phase: sm = float[128*132] (67584 B) aliases the whole block
  __shared__ __align__(16) unsigned char ldsraw[TM*264*2 + 2*LSEG*72*2];
  __shared__ float cs[LSEG];
  __shared__ float cs2[LSEG];
  __shared__ __align__(16) float b1s[2][ADIM];

  unsigned short* xbuf = reinterpret_cast<unsigned short*>(ldsraw);
  unsigned short* kqb  = reinterpret_cast<unsigned short*>(ldsraw + TM*264*2);
  float* sm = reinterpret_cast<float*>(ldsraw);

  const int tid  = threadIdx.x;
  const int lane = tid & 63;
  const int wid  = tid >> 6;                 // 0..7

  const int frow = lane & 15;
  const int kg   = lane >> 4;
  const int koff = kg * 8;
  const int crow = kg * 4;
  const int ccol = frow;
  const int rt  = wid >> 1;                  // L1 row tile (0..3)
  const int at0 = (wid & 1) * 2;             // L1 a-col tile base (0/2)

  // B1 (both paths) -> LDS; read first in L1(t=0) after 3 barriers
  if(tid < 2*ADIM) b1s[tid >> 6][tid & 63] = (tid < ADIM ? B1k : B1q)[tid & 63];

  const size_t rbase = (size_t)blockIdx.x * LSEG;   // segment row base

  // ---- W0 slice (k-path) resident: 8 ks x 2 h-tiles = 64 VGPRs ----
  bf16x8 w0f[8][2];
  #pragma unroll
  for(int ks=0; ks<8; ++ks)
    #pragma unroll
    for(int htl=0; htl<2; ++htl)
      w0f[ks][htl] = *reinterpret_cast<const bf16x8*>(
          W0k + (((wid*2 + htl)*8 + ks)*64 + lane)*8);
  float2 b0p = *reinterpret_cast<const float2*>(&B0k[wid*32 + 2*ccol]);

  // prologue: load X(tile 0) = Xk rows [rbase, rbase+64)
  float4 xr[8];
  {
    const float4* Xv = reinterpret_cast<const float4*>(Xk + rbase * DDIM);
    #pragma unroll
    for(int it=0; it<8; ++it) xr[it] = Xv[it*512 + tid];
  }

  for(int t=0; t<4; ++t){
    const int th = t & 1;          // row half within segment
    (void)th;

    if(t == 2){                    // path switch: reload W0 slice + bias (regs, no sync)
      #pragma unroll
      for(int ks=0; ks<8; ++ks)
        #pragma unroll
        for(int htl=0; htl<2; ++htl)
          w0f[ks][htl] = *reinterpret_cast<const bf16x8*>(
              W0q + (((wid*2 + htl)*8 + ks)*64 + lane)*8);
      b0p = *reinterpret_cast<const float2*>(&B0q[wid*32 + 2*ccol]);
    }

    // stage-write X(t) -> xbuf (bf16 pack); prior tile's H-readers done (sync 4)
    #pragma unroll
    for(int it=0; it<8; ++it){
      int idx = it*512 + tid;
      int r = idx >> 6, c4 = idx & 63;
      uint2 pk = { pk2bf(xr[it].x, xr[it].y), pk2bf(xr[it].z, xr[it].w) };
      *reinterpret_cast<uint2*>(&xbuf[r*264 + c4*4]) = pk;
    }

    // issue X(t+1) loads (regs); in flight under L0
    if(t < 3){
      const float* Xn = (((t+1) >> 1) ? Xq : Xk);
      const float4* Xv = reinterpret_cast<const float4*>(
          Xn + (rbase + (size_t)((t+1) & 1) * TM) * DDIM);
      #pragma unroll
      for(int it=0; it<8; ++it) xr[it] = Xv[it*512 + tid];
    }
    __syncthreads();               // (1) X(t) visible

    // ---- layer 0: LDS-A (mt=4) x register-B (nt=2) ----
    f32x4 acc[4][2];
    #pragma unroll
    for(int m=0;m<4;++m){ acc[m][0] = (f32x4){0.f,0.f,0.f,0.f};
                          acc[m][1] = (f32x4){0.f,0.f,0.f,0.f}; }
    #pragma unroll
    for(int ks=0; ks<8; ++ks){
      bf16x8 a[4];
      #pragma unroll
      for(int mt=0; mt<4; ++mt)
        a[mt] = *reinterpret_cast<const bf16x8*>(&xbuf[(mt*16 + frow)*264 + ks*32 + koff]);
      #pragma unroll
      for(int mt=0; mt<4; ++mt){
        acc[mt][0] = __builtin_amdgcn_mfma_f32_16x16x32_bf16(a[mt], w0f[ks][0], acc[mt][0], 0, 0, 0);
        acc[mt][1] = __builtin_amdgcn_mfma_f32_16x16x32_bf16(a[mt], w0f[ks][1], acc[mt][1], 0, 0, 0);
      }
    }
    __syncthreads();               // (2) all L0 reads done; xbuf dead

    // epilogue: bias + leaky -> H, aliased into xbuf (packed dword per pair)
    #pragma unroll
    for(int mt=0; mt<4; ++mt){
      #pragma unroll
      for(int r=0; r<4; ++r){
        float x0 = acc[mt][0][r] + b0p.x;
        float x1 = acc[mt][1][r] + b0p.y;
        x0 = x0 > 0.f ? x0 : 0.01f * x0;
        x1 = x1 > 0.f ? x1 : 0.01f * x1;
        *reinterpret_cast<unsigned int*>(
            &xbuf[(mt*16 + crow + r)*264 + wid*32 + 2*ccol]) = pk2bf(x0, x1);
      }
    }

    // W1 fragments (transient, L2-hot)
    const unsigned short* W1p = ((t >> 1) ? W1q : W1k);
    bf16x8 w1f[2][8];
    #pragma unroll
    for(int tt=0; tt<2; ++tt)
      #pragma unroll
      for(int ks=0; ks<8; ++ks)
        w1f[tt][ks] = *reinterpret_cast<const bf16x8*>(
            W1p + (((at0+tt)*8 + ks)*64 + lane)*8);
    __syncthreads();               // (3) H visible

    // ---- layer 1, swapped operands: D = W1 * H -> D[a][m] ----
    f32x4 acc2[2];
    acc2[0] = (f32x4){0.f,0.f,0.f,0.f};
    acc2[1] = (f32x4){0.f,0.f,0.f,0.f};
    #pragma unroll
    for(int ks=0; ks<8; ++ks){
      bf16x8 ah = *reinterpret_cast<const bf16x8*>(&xbuf[(rt*16 + frow)*264 + ks*32 + koff]);
      acc2[0] = __builtin_amdgcn_mfma_f32_16x16x32_bf16(w1f[0][ks], ah, acc2[0], 0, 0, 0);
      acc2[1] = __builtin_amdgcn_mfma_f32_16x16x32_bf16(w1f[1][ks], ah, acc2[1], 0, 0, 0);
    }
    {
      // bias from LDS; write K/Q fragment rows into kq region (separate from
      // xbuf -> no collision with live H). Layout == old seg staging:
      // kq[path][row*72 + a], row = half*64 + rt*16 + ccol, a-runs of 4.
      const float4 b1q0 = *reinterpret_cast<const float4*>(&b1s[t >> 1][(at0  )*16 + crow]);
      const float4 b1q1 = *reinterpret_cast<const float4*>(&b1s[t >> 1][(at0+1)*16 + crow]);
      unsigned short* kqp = kqb + (t >> 1) * (LSEG * 72);
      const int orow = (t & 1)*TM + rt*16 + ccol;
      uint2 o0 = { pk2bf(acc2[0][0] + b1q0.x, acc2[0][1] + b1q0.y),
                   pk2bf(acc2[0][2] + b1q0.z, acc2[0][3] + b1q0.w) };
      *reinterpret_cast<uint2*>(&kqp[orow*72 + at0*16 + crow]) = o0;
      uint2 o1 = { pk2bf(acc2[1][0] + b1q1.x, acc2[1][1] + b1q1.y),
                   pk2bf(acc2[1][2] + b1q1.z, acc2[1][3] + b1q1.w) };
      *reinterpret_cast<uint2*>(&kqp[orow*72 + (at0+1)*16 + crow]) = o1;
    }
    __syncthreads();               // (4) H reads done (next stage-write safe);
                                   //     after t=3: kq fully visible
  }

  // ================= seg phase (verbatim port, work gated tid<256) =========
  unsigned short* kt = kqb;                  // [128][72] bf16
  unsigned short* qt = kqb + LSEG * 72;

  {
    f32x4 sacc[8][2];
    if(tid < 256){
      const int arow = lane & 15;
      #pragma unroll
      for(int i=0;i<8;++i){ sacc[i][0] = (f32x4){0.f,0.f,0.f,0.f}; sacc[i][1] = (f32x4){0.f,0.f,0.f,0.f}; }
      #pragma unroll
      for(int ks=0; ks<2; ++ks){
        bf16x8 a[8], b[2];
        #pragma unroll
        for(int mt=0;mt<8;++mt)
          a[mt] = *reinterpret_cast<const bf16x8*>(&kt[(mt*16 + arow)*72 + ks*32 + koff]);
        #pragma unroll
        for(int nt=0;nt<2;++nt)
          b[nt] = *reinterpret_cast<const bf16x8*>(&qt[(wid*32 + nt*16 + arow)*72 + ks*32 + koff]);
        #pragma unroll
        for(int mt=0;mt<8;++mt)
          #pragma unroll
          for(int nt=0;nt<2;++nt)
            sacc[mt][nt] = __builtin_amdgcn_mfma_f32_16x16x32_bf16(a[mt], b[nt], sacc[mt][nt], 0, 0, 0);
      }
    }
    __syncthreads();     // kq reads done; sm scatter may overwrite kq bytes

    if(tid < 256){
      const int scrow = (lane >> 4) * 4;
      const int sccol = lane & 15;
      #pragma unroll
      for(int mt=0;mt<8;++mt)
        #pragma unroll
        for(int nt=0;nt<2;++nt){
          int col = wid*32 + nt*16 + sccol;
          #pragma unroll
          for(int r=0;r<4;++r)
            sm[(mt*16 + scrow + r)*132 + col] = sacc[mt][nt][r];
        }
    }
  }
  __syncthreads();

  float p[64];
  if(tid < 256){
    const int srow = tid >> 1, shalf = tid & 1;
    float* Mrow = &sm[srow*132 + shalf*64];
    #pragma unroll
    for(int j=0;j<64;j+=4){
      float4 v = *reinterpret_cast<const float4*>(Mrow + j);
      p[j] = v.x; p[j+1] = v.y; p[j+2] = v.z; p[j+3] = v.w;
    }
    float mx = p[0];
    #pragma unroll
    for(int j=1;j<64;++j) mx = fmaxf(mx, p[j]);
    mx = fmaxf(mx, __shfl_xor(mx, 1));
    float s = 0.f;
    #pragma unroll
    for(int j=0;j<64;++j){ p[j] = __expf(p[j] - mx); s += p[j]; }
    s += __shfl_xor(s, 1);
    float inv = 1.f / s;
    #pragma unroll
    for(int j=0;j<64;++j) p[j] *= inv;
    #pragma unroll
    for(int j=0;j<64;j+=4)
      *reinterpret_cast<float4*>(Mrow + j) = make_float4(p[j], p[j+1], p[j+2], p[j+3]);
  }
  __syncthreads();

  // ---- colsum pass 1 ----
  {
    const int col = tid & 127, hf = tid >> 7;
    float ps = 0.f;
    if(tid < 256){
      #pragma unroll 8
      for(int l=hf*64; l<hf*64+64; ++l) ps += sm[l*132 + col];
      if(hf) cs2[col] = ps;
    }
    __syncthreads();
    if(tid < LSEG){
      float cssum = ps + cs2[tid];
      float v  = cssum + EPSF;
      float lp = -__logf(v) * v;
      #pragma unroll
      for(int o=1;o<64;o<<=1) lp += __shfl_xor(lp, o);
      if(lane == 0) atomicAdd(lossp, lp);
      cs[tid] = 1.f / ((cssum + 128.f * EPSF) * 128.f);
    }
  }
  __syncthreads();

  if(tid < 256){
    const int srow = tid >> 1, shalf = tid & 1;
    float* Mrow = &sm[srow*132 + shalf*64];
    float rs = 0.f;
    #pragma unroll
    for(int j=0;j<64;++j){ p[j] = (p[j] + EPSF) * cs[shalf*64 + j]; rs += p[j]; }
    rs += __shfl_xor(rs, 1);
    float inv2 = 1.f / (rs * 128.f);
    #pragma unroll
    for(int j=0;j<64;++j) p[j] *= inv2;
    #pragma unroll
    for(int j=0;j<64;j+=4)
      *reinterpret_cast<float4*>(Mrow + j) = make_float4(p[j], p[j+1], p[j+2], p[j+3]);
  }
  __syncthreads();

  // ---- colsum pass 2 ----
  {
    const int col = tid & 127, hf = tid >> 7;
    float ps = 0.f;
    if(tid < 256){
      #pragma unroll 8
      for(int l=hf*64; l<hf*64+64; ++l) ps += sm[l*132 + col];
      if(hf) cs2[col] = ps;
    }
    __syncthreads();
    if(tid < LSEG) cs[tid] = 1.f / ((ps + cs2[tid]) * 128.f);
  }
  __syncthreads();

  if(tid < 256){
    const int srow = tid >> 1, shalf = tid & 1;
    float* Mrow = &sm[srow*132 + shalf*64];
    float rs = 0.f;
    #pragma unroll
    for(int j=0;j<64;++j){ p[j] *= cs[shalf*64 + j]; rs += p[j]; }
    rs += __shfl_xor(rs, 1);
    float inv4 = 1.f / (rs * 128.f);
    #pragma unroll
    for(int j=0;j<64;++j) p[j] *= inv4;
    #pragma unroll
    for(int j=0;j<64;j+=4)
      *reinterpret_cast<float4*>(Mrow + j) = make_float4(p[j], p[j+1], p[j+2], p[j+3]);
  }
  __syncthreads();

  // ---- colsum pass 3 ----
  {
    const int col = tid & 127, hf = tid >> 7;
    float ps = 0.f;
    if(tid < 256){
      #pragma unroll 8
      for(int l=hf*64; l<hf*64+64; ++l) ps += sm[l*132 + col];
      if(hf) cs2[col] = ps;
    }
    __syncthreads();
    if(tid < LSEG) cs[tid] = 1.f / ((ps + cs2[tid]) * 128.f);
  }
  __syncthreads();

  // final scaled output (all 512 threads: 8 iters of float4)
  float* outseg = Wout + (long)blockIdx.x * (LSEG*LSEG);
  #pragma unroll
  for(int it=0; it<8; ++it){
    int f = it*2048 + tid*4;
    int r = f >> 7, c = f & 127;
    float4 v = *reinterpret_cast<const float4*>(&sm[r*132 + c]);
    v.x *= cs[c]; v.y *= cs[c+1]; v.z *= cs[c+2]; v.w *= cs[c+3];
    *reinterpret_cast<float4*>(outseg + f) = v;
  }
}

extern "C" void kernel_launch(void* const* d_in, const int* in_sizes, int n_in,
                              void* d_out, int out_size, void* d_ws, size_t ws_size,
                              hipStream_t stream) {
  (void)in_sizes; (void)n_in; (void)ws_size;
  const float* yhat = (const float*)d_in[0];
  const float* y    = (const float*)d_in[1];
  const float* k0w  = (const float*)d_in[2];
  const float* k0b  = (const float*)d_in[3];
  const float* k1w  = (const float*)d_in[4];
  const float* k1b  = (const float*)d_in[5];
  const float* q0w  = (const float*)d_in[6];
  const float* q0b  = (const float*)d_in[7];
  const float* q1w  = (const float*)d_in[8];
  const float* q1b  = (const float*)d_in[9];

  unsigned short* w0k = (unsigned short*)d_ws;             // prepacked fragment-major
  unsigned short* w1k = w0k + HDIM * DDIM;
  unsigned short* w0q = w1k + ADIM * HDIM;
  unsigned short* w1q = w0q + HDIM * DDIM;

  float* Wout  = (float*)d_out;
  float* lossp = Wout + (size_t)(out_size - 1);
  hipMemsetAsync(lossp, 0, sizeof(float), stream);

  cvt4_kernel<<<640, 256, 0, stream>>>(k0w, k1w, q0w, q1w, w0k, w1k, w0q, w1q);

  fused_kernel<<<NSEG, 512, 0, stream>>>(y, yhat,
                                         w0k, k0b, w1k, k1b,
                                         w0q, q0b, w1q, q1b,
                                         Wout, lossp);
}

// Round 5
// 215.630 us; speedup vs baseline: 1.1611x; 1.1611x over previous
//
#include <hip/hip_runtime.h>
#include <hip/hip_bf16.h>

#define NROWS 262144
#define DDIM 256
#define HDIM 256
#define ADIM 64
#define LSEG 128
#define NSEG 2048
#define EPSF 1e-6f
#define TM 64                     // rows per tile
#define NBPP 256                  // blocks per path
#define TPB 16                    // tiles per block (256*16*64 = 262144)

typedef __attribute__((ext_vector_type(8))) short bf16x8;
typedef __attribute__((ext_vector_type(4))) float f32x4;

__device__ __forceinline__ unsigned short f2bf(float x){
  unsigned u = __float_as_uint(x);
  u += 0x7FFFu + ((u >> 16) & 1u);   // round-to-nearest-even
  return (unsigned short)(u >> 16);
}

// packed f32x2 -> bf16x2 (compiler lowers to v_cvt_pk_bf16_f32)
__device__ __forceinline__ unsigned int pk2bf(float a, float b){
  union { __hip_bfloat162 h2; unsigned int u; } cv;
  cv.h2 = __float22bfloat162_rn(make_float2(a, b));
  return cv.u;
}

// Weight prepack, fragment-major (validated: absmax 1.9e-6):
// dst[(((h>>4)*8 + (k>>5))*64 + ((k>>3)&3)*16 + (h&15))*8 + (k&7)] = bf16(W[h][k])
__device__ __forceinline__ int fragidx(int h, int k){
  return (((h >> 4)*8 + (k >> 5))*64 + ((k >> 3) & 3)*16 + (h & 15))*8 + (k & 7);
}

// W0-only variant: interleave h within each 32-col wave group so the two
// nt-fragments of a wave produce ADJACENT h columns (h = base + 2*frow + htl)
// -> L0 epilogue writes H as packed dwords. Correctness-verified R1-R4.
__device__ __forceinline__ int fragidx0(int h, int k){
  int hh = (h & ~31) | ((h & 1) << 4) | ((h & 31) >> 1);
  return fragidx(hh, k);
}

__global__ void cvt4_kernel(const float* __restrict__ s0, const float* __restrict__ s1,
                            const float* __restrict__ s2, const float* __restrict__ s3,
                            unsigned short* __restrict__ d0, unsigned short* __restrict__ d1,
                            unsigned short* __restrict__ d2, unsigned short* __restrict__ d3){
  int i = blockIdx.x * blockDim.x + threadIdx.x;
  if(i < 65536){                       // W0k [256][256] (h-interleaved)
    d0[fragidx0(i >> 8, i & 255)] = f2bf(s0[i]);
  } else if(i < 81920){                // W1k [64][256]
    int j = i - 65536;
    d1[fragidx(j >> 8, j & 255)] = f2bf(s1[j]);
  } else if(i < 147456){               // W0q (h-interleaved)
    int j = i - 81920;
    d2[fragidx0(j >> 8, j & 255)] = f2bf(s2[j]);
  } else {                             // W1q
    int j = i - 147456;
    d3[fragidx(j >> 8, j & 255)] = f2bf(s3[j]);
  }
}

// Fused 2-layer MLP — FINAL configuration (R3-verified, 174-177us):
// __syncthreads double-buffered structure. SESSION LEDGER of refuted
// alternatives (do not retry):
//   - lgk-only raw barriers:        234us total (R1) — hbm_gbps FELL
//   - + rotated t+2 prefetch:       241us total (R2) — hbm_gbps FELL again
//   - mlp+seg fusion (1 blk/seg):   250us total (R4) — single-buffer 4-barrier
//     MLP phase + half-idle seg phase cost 70us to save 20us of traffic
// SQ_LDS_BANK_CONFLICT 1.049e7 is STRUCTURAL (identical across 3 write
// layouts): ds_read_b128 intrinsic cost, not a fixable conflict.
// Occupancy cliffs pinning this design: VGPR must stay <=128 for 16 waves/CU
// (nt=4 would need +64 VGPR for W0 regs); LDS 67.6KB vs 80KB/2-block budget
// (3 blocks/CU would need <=53KB — impossible with dbuf 64x264 tiles).
// __launch_bounds__(512,2): REQUIRED — (512,4) collapses allocator to
// VGPR=64 + spills (3x reproduced).
__global__ __launch_bounds__(512, 2) void mlp_kernel(
    const float* __restrict__ Xk, const float* __restrict__ Xq,
    const unsigned short* __restrict__ W0k, const float* __restrict__ B0k,
    const unsigned short* __restrict__ W1k, const float* __restrict__ B1k,
    const unsigned short* __restrict__ W0q, const float* __restrict__ B0q,
    const unsigned short* __restrict__ W1q, const float* __restrict__ B1q,
    unsigned short* __restrict__ OUTk, unsigned short* __restrict__ OUTq)
{
  __shared__ __align__(16) unsigned short xls[2][TM * 264];  // 67.6 KB; H aliases xls[cur]
  __shared__ __align__(16) float b1s[ADIM];                  // B1 staged once

  const int tid  = threadIdx.x;
  const int lane = tid & 63;
  const int wid  = tid >> 6;                 // 0..7
  const bool qpath = blockIdx.x >= NBPP;
  const int  bp   = blockIdx.x & (NBPP - 1);

  const float* X = qpath ? Xq : Xk;
  const unsigned short* W0p = qpath ? W0q : W0k;
  const float* B0 = qpath ? B0q : B0k;
  const unsigned short* W1p = qpath ? W1q : W1k;
  const float* B1 = qpath ? B1q : B1k;
  unsigned short* OUT = qpath ? OUTq : OUTk;

  const int frow = lane & 15;
  const int kg   = lane >> 4;
  const int koff = kg * 8;
  const int crow = kg * 4;
  const int ccol = frow;

  // B1 -> LDS (covered by the prologue barrier)
  if(tid < ADIM) b1s[tid] = B1[tid];

  // ---- W0 slice resident in registers: 8 ks x 2 h-tiles = 64 VGPRs ----
  bf16x8 w0f[8][2];
  #pragma unroll
  for(int ks=0; ks<8; ++ks)
    #pragma unroll
    for(int htl=0; htl<2; ++htl)
      w0f[ks][htl] = *reinterpret_cast<const bf16x8*>(
          W0p + (((wid*2 + htl)*8 + ks)*64 + lane)*8);

  // bias for the interleaved-h pair this lane produces: h = wid*32 + 2*ccol + {0,1}
  const float2 b0p = *reinterpret_cast<const float2*>(&B0[wid*32 + 2*ccol]);
  const int rt  = wid >> 1;                  // L1 row tile (0..3)
  const int at0 = (wid & 1) * 2;             // L1 a-col tile base (0/2)

  // ---- prologue: stage tile 0 ----
  float4 xr[8];
  {
    const float4* Xv = reinterpret_cast<const float4*>(X + (size_t)bp * TM * DDIM);
    #pragma unroll
    for(int it=0; it<8; ++it) xr[it] = Xv[it*512 + tid];
    #pragma unroll
    for(int it=0; it<8; ++it){
      int idx = it*512 + tid;
      int r = idx >> 6, c4 = idx & 63;
      uint2 pk = { pk2bf(xr[it].x, xr[it].y), pk2bf(xr[it].z, xr[it].w) };
      *reinterpret_cast<uint2*>(&xls[0][r*264 + c4*4]) = pk;
    }
  }
  __syncthreads();

  for(int t=0; t<TPB; ++t){
    const int cur = t & 1;
    const size_t row0 = ((size_t)bp + (size_t)t * NBPP) * TM;

    // issue X(t+1) loads; in flight under this whole tile's L0
    if(t < TPB-1){
      const float4* Xn = reinterpret_cast<const float4*>(
          X + ((size_t)bp + (size_t)(t+1) * NBPP) * TM * DDIM);
      #pragma unroll
      for(int it=0; it<8; ++it) xr[it] = Xn[it*512 + tid];
    }

    // ---- layer 0: LDS-A (mt=4) x register-B (nt=2) ----
    f32x4 acc[4][2];
    #pragma unroll
    for(int m=0;m<4;++m){ acc[m][0] = (f32x4){0.f,0.f,0.f,0.f};
                          acc[m][1] = (f32x4){0.f,0.f,0.f,0.f}; }
    const unsigned short* xc = xls[cur];
    #pragma unroll
    for(int ks=0; ks<8; ++ks){
      bf16x8 a[4];
      #pragma unroll
      for(int mt=0; mt<4; ++mt)
        a[mt] = *reinterpret_cast<const bf16x8*>(&xc[(mt*16 + frow)*264 + ks*32 + koff]);
      #pragma unroll
      for(int mt=0; mt<4; ++mt){
        acc[mt][0] = __builtin_amdgcn_mfma_f32_16x16x32_bf16(a[mt], w0f[ks][0], acc[mt][0], 0, 0, 0);
        acc[mt][1] = __builtin_amdgcn_mfma_f32_16x16x32_bf16(a[mt], w0f[ks][1], acc[mt][1], 0, 0, 0);
      }
    }
    __syncthreads();   // A: all waves' L0 reads of xls[cur] done
                       //    (also: all waves' L1(t-1) reads of xls[cur^1] done)

    // epilogue: bias + leaky -> H, aliased into xls[cur]; one packed dword
    // per (mt,r) at column 2*ccol
    unsigned short* hc = xls[cur];
    #pragma unroll
    for(int mt=0; mt<4; ++mt){
      #pragma unroll
      for(int r=0; r<4; ++r){
        float x0 = acc[mt][0][r] + b0p.x;
        float x1 = acc[mt][1][r] + b0p.y;
        x0 = x0 > 0.f ? x0 : 0.01f * x0;
        x1 = x1 > 0.f ? x1 : 0.01f * x1;
        *reinterpret_cast<unsigned int*>(
            &hc[(mt*16 + crow + r)*264 + wid*32 + 2*ccol]) = pk2bf(x0, x1);
      }
    }

    // stage-write X(t+1) into xls[cur^1] (H(t-1) there; its readers done at A)
    if(t < TPB-1){
      #pragma unroll
      for(int it=0; it<8; ++it){
        int idx = it*512 + tid;
        int r = idx >> 6, c4 = idx & 63;
        uint2 pk = { pk2bf(xr[it].x, xr[it].y), pk2bf(xr[it].z, xr[it].w) };
        *reinterpret_cast<uint2*>(&xls[cur^1][r*264 + c4*4]) = pk;
      }
    }

    // W1 fragments (transient, L2-hot, coalesced)
    bf16x8 w1f[2][8];
    #pragma unroll
    for(int tt=0; tt<2; ++tt)
      #pragma unroll
      for(int ks=0; ks<8; ++ks)
        w1f[tt][ks] = *reinterpret_cast<const bf16x8*>(
            W1p + (((at0+tt)*8 + ks)*64 + lane)*8);
    __syncthreads();   // B: H(t) + X(t+1) visible

    // ---- layer 1, swapped operands: D = W1 * H -> D[a][m] ----
    // lane holds 4 consecutive a for row m=ccol -> packed uint2 OUT stores
    f32x4 acc2[2];
    acc2[0] = (f32x4){0.f,0.f,0.f,0.f};
    acc2[1] = (f32x4){0.f,0.f,0.f,0.f};
    #pragma unroll
    for(int ks=0; ks<8; ++ks){
      bf16x8 ah = *reinterpret_cast<const bf16x8*>(&hc[(rt*16 + frow)*264 + ks*32 + koff]);
      acc2[0] = __builtin_amdgcn_mfma_f32_16x16x32_bf16(w1f[0][ks], ah, acc2[0], 0, 0, 0);
      acc2[1] = __builtin_amdgcn_mfma_f32_16x16x32_bf16(w1f[1][ks], ah, acc2[1], 0, 0, 0);
    }
    {
      // bias from LDS (loaded once at kernel start)
      const float4 b1q0 = *reinterpret_cast<const float4*>(&b1s[(at0  )*16 + crow]);
      const float4 b1q1 = *reinterpret_cast<const float4*>(&b1s[(at0+1)*16 + crow]);
      const size_t obase = (row0 + rt*16 + ccol) * ADIM;
      uint2 o0 = { pk2bf(acc2[0][0] + b1q0.x, acc2[0][1] + b1q0.y),
                   pk2bf(acc2[0][2] + b1q0.z, acc2[0][3] + b1q0.w) };
      *reinterpret_cast<uint2*>(&OUT[obase + at0*16 + crow]) = o0;
      uint2 o1 = { pk2bf(acc2[1][0] + b1q1.x, acc2[1][1] + b1q1.y),
                   pk2bf(acc2[1][2] + b1q1.z, acc2[1][3] + b1q1.w) };
      *reinterpret_cast<uint2*>(&OUT[obase + (at0+1)*16 + crow]) = o1;
    }
    // no END barrier: tile t+1's writes into xls[cur] occur only after A(t+1),
    // which orders them after every wave's L1(t) reads.
  }
}

// Per-segment: M = K@Q^T, softmax(rows), loss colsums, sinkhorn x5, write W.
// Measured AT the HBM roofline: 201 MB traffic / ~32 us = 6.3 TB/s.
__global__ __launch_bounds__(256) void seg_kernel(
    const unsigned short* __restrict__ Kb,   // [N,64] bf16
    const unsigned short* __restrict__ Qb,   // [N,64] bf16
    float* __restrict__ Wout,                // [NSEG,128,128] f32
    float* __restrict__ lossp)               // scalar accumulator (pre-zeroed)
{
  __shared__ __align__(16) float sm[LSEG * 132];
  __shared__ float cs[LSEG];
  __shared__ float cs2[LSEG];                     // upper-half partials
  const int tid  = threadIdx.x;
  const int lane = tid & 63;
  const int wid  = tid >> 6;
  const long sbase = (long)blockIdx.x * (LSEG * ADIM);

  unsigned short* kt = reinterpret_cast<unsigned short*>(sm);  // [128][72]
  unsigned short* qt = kt + LSEG * 72;

  {
    const uint4* Kv = reinterpret_cast<const uint4*>(Kb + sbase);
    const uint4* Qv = reinterpret_cast<const uint4*>(Qb + sbase);
    #pragma unroll
    for(int it=0; it<4; ++it){
      int idx = it*256 + tid;
      int r = idx >> 3, c8 = (idx & 7) * 8;
      *reinterpret_cast<uint4*>(&kt[r*72 + c8]) = Kv[idx];
      *reinterpret_cast<uint4*>(&qt[r*72 + c8]) = Qv[idx];
    }
  }
  __syncthreads();

  const int arow = lane & 15;
  const int koff = (lane >> 4) * 8;
  f32x4 acc[8][2];
  #pragma unroll
  for(int i=0;i<8;++i){ acc[i][0] = (f32x4){0.f,0.f,0.f,0.f}; acc[i][1] = (f32x4){0.f,0.f,0.f,0.f}; }
  #pragma unroll
  for(int ks=0; ks<2; ++ks){
    bf16x8 a[8], b[2];
    #pragma unroll
    for(int mt=0;mt<8;++mt)
      a[mt] = *reinterpret_cast<const bf16x8*>(&kt[(mt*16 + arow)*72 + ks*32 + koff]);
    #pragma unroll
    for(int nt=0;nt<2;++nt)
      b[nt] = *reinterpret_cast<const bf16x8*>(&qt[(wid*32 + nt*16 + arow)*72 + ks*32 + koff]);
    #pragma unroll
    for(int mt=0;mt<8;++mt)
      #pragma unroll
      for(int nt=0;nt<2;++nt)
        acc[mt][nt] = __builtin_amdgcn_mfma_f32_16x16x32_bf16(a[mt], b[nt], acc[mt][nt], 0, 0, 0);
  }
  __syncthreads();

  const int crow = (lane >> 4) * 4;
  const int ccol = lane & 15;
  #pragma unroll
  for(int mt=0;mt<8;++mt)
    #pragma unroll
    for(int nt=0;nt<2;++nt){
      int col = wid*32 + nt*16 + ccol;
      #pragma unroll
      for(int r=0;r<4;++r)
        sm[(mt*16 + crow + r)*132 + col] = acc[mt][nt][r];
    }
  __syncthreads();

  const int row  = tid >> 1;
  const int half = tid & 1;
  float* Mrow = &sm[row*132 + half*64];
  float p[64];
  #pragma unroll
  for(int j=0;j<64;j+=4){
    float4 v = *reinterpret_cast<const float4*>(Mrow + j);
    p[j] = v.x; p[j+1] = v.y; p[j+2] = v.z; p[j+3] = v.w;
  }
  float mx = p[0];
  #pragma unroll
  for(int j=1;j<64;++j) mx = fmaxf(mx, p[j]);
  mx = fmaxf(mx, __shfl_xor(mx, 1));
  float s = 0.f;
  #pragma unroll
  for(int j=0;j<64;++j){ p[j] = __expf(p[j] - mx); s += p[j]; }
  s += __shfl_xor(s, 1);
  float inv = 1.f / s;
  #pragma unroll
  for(int j=0;j<64;++j) p[j] *= inv;
  #pragma unroll
  for(int j=0;j<64;j+=4)
    *reinterpret_cast<float4*>(Mrow + j) = make_float4(p[j], p[j+1], p[j+2], p[j+3]);
  __syncthreads();

  // ---- colsum pass 1 (split rows across both thread-halves) ----
  {
    const int col = tid & 127, hf = tid >> 7;
    float ps = 0.f;
    #pragma unroll 8
    for(int l=hf*64; l<hf*64+64; ++l) ps += sm[l*132 + col];
    if(hf) cs2[col] = ps;
    __syncthreads();
    if(tid < LSEG){
      float cssum = ps + cs2[tid];
      float v  = cssum + EPSF;
      float lp = -__logf(v) * v;
      #pragma unroll
      for(int o=1;o<64;o<<=1) lp += __shfl_xor(lp, o);
      if(lane == 0) atomicAdd(lossp, lp);
      cs[tid] = 1.f / ((cssum + 128.f * EPSF) * 128.f);
    }
  }
  __syncthreads();

  float rs = 0.f;
  #pragma unroll
  for(int j=0;j<64;++j){ p[j] = (p[j] + EPSF) * cs[half*64 + j]; rs += p[j]; }
  rs += __shfl_xor(rs, 1);
  float inv2 = 1.f / (rs * 128.f);
  #pragma unroll
  for(int j=0;j<64;++j) p[j] *= inv2;
  #pragma unroll
  for(int j=0;j<64;j+=4)
    *reinterpret_cast<float4*>(Mrow + j) = make_float4(p[j], p[j+1], p[j+2], p[j+3]);
  __syncthreads();

  // ---- colsum pass 2 ----
  {
    const int col = tid & 127, hf = tid >> 7;
    float ps = 0.f;
    #pragma unroll 8
    for(int l=hf*64; l<hf*64+64; ++l) ps += sm[l*132 + col];
    if(hf) cs2[col] = ps;
    __syncthreads();
    if(tid < LSEG) cs[tid] = 1.f / ((ps + cs2[tid]) * 128.f);
  }
  __syncthreads();

  rs = 0.f;
  #pragma unroll
  for(int j=0;j<64;++j){ p[j] *= cs[half*64 + j]; rs += p[j]; }
  rs += __shfl_xor(rs, 1);
  float inv4 = 1.f / (rs * 128.f);
  #pragma unroll
  for(int j=0;j<64;++j) p[j] *= inv4;
  #pragma unroll
  for(int j=0;j<64;j+=4)
    *reinterpret_cast<float4*>(Mrow + j) = make_float4(p[j], p[j+1], p[j+2], p[j+3]);
  __syncthreads();

  // ---- colsum pass 3 ----
  {
    const int col = tid & 127, hf = tid >> 7;
    float ps = 0.f;
    #pragma unroll 8
    for(int l=hf*64; l<hf*64+64; ++l) ps += sm[l*132 + col];
    if(hf) cs2[col] = ps;
    __syncthreads();
    if(tid < LSEG) cs[tid] = 1.f / ((ps + cs2[tid]) * 128.f);
  }
  __syncthreads();

  float* outseg = Wout + (long)blockIdx.x * (LSEG*LSEG);
  #pragma unroll
  for(int it=0; it<16; ++it){
    int f = it*1024 + tid*4;
    int r = f >> 7, c = f & 127;
    float4 v = *reinterpret_cast<const float4*>(&sm[r*132 + c]);
    v.x *= cs[c]; v.y *= cs[c+1]; v.z *= cs[c+2]; v.w *= cs[c+3];
    *reinterpret_cast<float4*>(outseg + f) = v;
  }
}

extern "C" void kernel_launch(void* const* d_in, const int* in_sizes, int n_in,
                              void* d_out, int out_size, void* d_ws, size_t ws_size,
                              hipStream_t stream) {
  (void)in_sizes; (void)n_in; (void)ws_size;
  const float* yhat = (const float*)d_in[0];
  const float* y    = (const float*)d_in[1];
  const float* k0w  = (const float*)d_in[2];
  const float* k0b  = (const float*)d_in[3];
  const float* k1w  = (const float*)d_in[4];
  const float* k1b  = (const float*)d_in[5];
  const float* q0w  = (const float*)d_in[6];
  const float* q0b  = (const float*)d_in[7];
  const float* q1w  = (const float*)d_in[8];
  const float* q1b  = (const float*)d_in[9];

  unsigned short* Kbuf = (unsigned short*)d_ws;            // [N,64] bf16
  unsigned short* Qbuf = Kbuf + (size_t)NROWS * ADIM;      // [N,64] bf16
  unsigned short* w0k  = Qbuf + (size_t)NROWS * ADIM;      // prepacked fragment-major
  unsigned short* w1k  = w0k + HDIM * DDIM;
  unsigned short* w0q  = w1k + ADIM * HDIM;
  unsigned short* w1q  = w0q + HDIM * DDIM;

  cvt4_kernel<<<640, 256, 0, stream>>>(k0w, k1w, q0w, q1w, w0k, w1k, w0q, w1q);

  mlp_kernel<<<2 * NBPP, 512, 0, stream>>>(y, yhat,
                                           w0k, k0b, w1k, k1b,
                                           w0q, q0b, w1q, q1b,
                                           Kbuf, Qbuf);

  float* Wout  = (float*)d_out;
  float* lossp = Wout + (size_t)(out_size - 1);
  hipMemsetAsync(lossp, 0, sizeof(float), stream);
  seg_kernel<<<NSEG, 256, 0, stream>>>(Kbuf, Qbuf, Wout, lossp);
}